// Round 8
// baseline (103.367 us; speedup 1.0000x reference)
//
#include <hip/hip_runtime.h>
#include <hip/hip_bf16.h>

typedef __attribute__((ext_vector_type(8))) short short8;
typedef __attribute__((ext_vector_type(4))) short short4v;
typedef __attribute__((ext_vector_type(4))) float f32x4;

// ws: A' [8192][128] bf16 (2MB) | B' [8192][128] bf16 (2MB) |
//     WoutT [128][1024] bf16 (256KB) | W12bf [64][256] bf16 (32KB)
#define WS_A   0
#define WS_B   (8192 * 128 * 2)
#define WS_WT  (2 * 8192 * 128 * 2)
#define WS_W12 (WS_WT + 128 * 1024 * 2)

static __device__ __forceinline__ short f2bf(float x) {
    __hip_bfloat16 h = __float2bfloat16(x);
    return *reinterpret_cast<short*>(&h);
}

typedef __attribute__((address_space(3))) unsigned int lds_u32;
typedef const __attribute__((address_space(1))) unsigned int glb_u32;
static __device__ __forceinline__ void stage16(const void* g, void* l) {
    __builtin_amdgcn_global_load_lds((glb_u32*)g, (lds_u32*)l, 16, 0, 0);
}

// ---------------- Kernel 0: Wout -> bf16 [z][ck]; W1|W2 -> bf16 [64 c][256 d] ----------------
__global__ __launch_bounds__(256) void k_prep(const float* __restrict__ Wout,
                                              const float* __restrict__ W1,
                                              const float* __restrict__ W2,
                                              __hip_bfloat16* __restrict__ WoutT,
                                              __hip_bfloat16* __restrict__ W12bf) {
    int idx = blockIdx.x * 256 + threadIdx.x;
    if (blockIdx.x < 512) {
        int z = idx >> 10, ck = idx & 1023;
        WoutT[idx] = __float2bfloat16(Wout[ck * 128 + z]);
    } else {
        idx -= 512 * 256;                  // 0..16383
        int c = idx >> 8, d = idx & 255;
        W12bf[idx] = __float2bfloat16(c < 32 ? W1[d * 32 + c] : W2[d * 32 + (c - 32)]);
    }
}

// ---------------- Kernel 1: LayerNorm + dual projection via MFMA (unchanged) ----------------
__global__ __launch_bounds__(256) void k_lnproj(const float* __restrict__ mm,
                                                const float* __restrict__ gamma,
                                                const float* __restrict__ beta,
                                                const float* __restrict__ b1,
                                                const float* __restrict__ b2,
                                                const __hip_bfloat16* __restrict__ W12bf,
                                                __hip_bfloat16* __restrict__ Ap,
                                                __hip_bfloat16* __restrict__ Bp) {
    __shared__ char sMN[4][8192];      // per-wave [16 rows][256 d] bf16, XOR-swizzled
    __shared__ char sW[32768];         // [64 c][256 d] bf16, XOR-swizzled (512B rows)
    const int t    = threadIdx.x;
    const int lane = t & 63;
    const int wid  = t >> 6;
    const int gw   = blockIdx.x * 4 + wid;   // 0..2047
    const int i_   = gw & 255;
    const int sb   = (gw >> 8) * 16;

    #pragma unroll
    for (int it = 0; it < 8; it++) {
        const int idx = it * 256 + t;
        const int row = idx >> 5;
        const int L   = (idx & 31) * 16;
        *(short8*)(sW + row * 512 + (L ^ ((row & 7) << 4))) =
            *(const short8*)((const short*)W12bf + idx * 8);
    }

    float4 g4  = *(const float4*)&gamma[lane * 4];
    float4 be4 = *(const float4*)&beta[lane * 4];
    char* my = sMN[wid];

    #pragma unroll
    for (int rr = 0; rr < 16; rr++) {
        float4 x = *(const float4*)&mm[((size_t)(sb + rr) * 256 + i_) * 256 + lane * 4];
        float s  = x.x + x.y + x.z + x.w;
        float ss = x.x * x.x + x.y * x.y + x.z * x.z + x.w * x.w;
        #pragma unroll
        for (int off = 32; off; off >>= 1) {
            s  += __shfl_xor(s, off);
            ss += __shfl_xor(ss, off);
        }
        float mu  = s * (1.f / 256.f);
        float var = ss * (1.f / 256.f) - mu * mu;
        float rs  = rsqrtf(var + 1e-5f);
        short4v v;
        v.x = f2bf((x.x - mu) * rs * g4.x + be4.x);
        v.y = f2bf((x.y - mu) * rs * g4.y + be4.y);
        v.z = f2bf((x.z - mu) * rs * g4.z + be4.z);
        v.w = f2bf((x.w - mu) * rs * g4.w + be4.w);
        *(short4v*)(my + rr * 512 + ((lane * 8) ^ ((rr & 7) << 4))) = v;
    }
    __syncthreads();

    const int g = lane >> 4, r16 = lane & 15;

    f32x4 acc[4];
    #pragma unroll
    for (int nf = 0; nf < 4; nf++) {
        int col = nf * 16 + r16;
        float bv = (col < 32) ? b1[col] : b2[col - 32];
        acc[nf] = (f32x4){bv, bv, bv, bv};
    }
    #pragma unroll
    for (int ks = 0; ks < 8; ks++) {
        const int L = ks * 64 + g * 16;
        short8 af = *(const short8*)(my + r16 * 512 + (L ^ ((r16 & 7) << 4)));
        #pragma unroll
        for (int nf = 0; nf < 4; nf++) {
            short8 bfv = *(const short8*)(sW + (nf * 16 + r16) * 512 + (L ^ ((r16 & 7) << 4)));
            acc[nf] = __builtin_amdgcn_mfma_f32_16x16x32_bf16(af, bfv, acc[nf], 0, 0, 0);
        }
    }
    #pragma unroll
    for (int nf = 0; nf < 4; nf++) {
        int col = nf * 16 + r16;
        short* Out = (short*)((col < 32) ? Ap : Bp);
        int cr = col & 31;
        short4v v;
        v.x = f2bf(acc[nf][0]); v.y = f2bf(acc[nf][1]);
        v.z = f2bf(acc[nf][2]); v.w = f2bf(acc[nf][3]);
        *(short4v*)&Out[(i_ * 32 + cr) * 128 + sb + g * 4] = v;
    }
}

// ---------------- Kernel 2: 128jk x 256ic tile, 64KB LDS -> 2 blocks/CU ----------------
// LDS 64KB: staging [0,48K): B 128x64 [0,16K) | A 256x64 [16K,48K). kh serial-reuse.
// After main: sP [32 p][1024 ck] bf16 = 64KB, granule swizzle gr^(p&7).
// EPI: 8 waves = 4 zg x 2 ik(ck-half); 16x16x32, 2pf x 2nf x 16ks; f32 reduce via LDS.
extern __shared__ char lds[];

__global__ __launch_bounds__(512, 4) void k_gemm8(const __hip_bfloat16* __restrict__ Apb,
                                                  const __hip_bfloat16* __restrict__ Bpb,
                                                  const __hip_bfloat16* __restrict__ WoutT,
                                                  const float* __restrict__ bout,
                                                  float* __restrict__ out) {
    const int t = threadIdx.x, lane = t & 63, wid = t >> 6;
    const int g = lane >> 4, r16 = lane & 15;
    const int wr = wid >> 2, wc = wid & 3;            // wr: jk half (64), wc: ic quarter (64)
    const int bid = (blockIdx.x & 7) * 256 + (blockIdx.x >> 3);   // XCD swizzle (2048%8==0)
    const int bi = bid >> 6, bj = bid & 63;           // bi: 32 ic-blocks, bj: 64 jk-blocks

    const short* gA = (const short*)Apb + (size_t)bi * 256 * 128;   // 256 ic rows
    const short* gB = (const short*)Bpb + (size_t)bj * 128 * 128;   // 128 jk rows

    const int srow8 = lane >> 3;
    const int sgran = (lane & 7) ^ srow8;             // pre-swizzled source granule

    f32x4 acc[4][4];
    #pragma unroll
    for (int mf = 0; mf < 4; mf++)
        #pragma unroll
        for (int nf = 0; nf < 4; nf++)
            acc[mf][nf] = (f32x4){0.f, 0.f, 0.f, 0.f};

    #pragma unroll
    for (int kh = 0; kh < 2; kh++) {
        // ---- stage kh half: B 128 rows (2 it), A 256 rows (4 it); 128B LDS rows
        #pragma unroll
        for (int it = 0; it < 2; it++) {
            const int row = it * 64 + wid * 8 + srow8;
            stage16(gB + row * 128 + kh * 64 + sgran * 8, lds + it * 8192 + wid * 1024);
        }
        #pragma unroll
        for (int it = 0; it < 4; it++) {
            const int row = it * 64 + wid * 8 + srow8;
            stage16(gA + row * 128 + kh * 64 + sgran * 8,
                    lds + 16384 + it * 8192 + wid * 1024);
        }
        asm volatile("s_waitcnt vmcnt(0)" ::: "memory");
        __builtin_amdgcn_s_barrier();

        #pragma unroll
        for (int ksl = 0; ksl < 2; ksl++) {
            short8 af[4], bfv[4];
            #pragma unroll
            for (int mf = 0; mf < 4; mf++) {
                const int row = wr * 64 + mf * 16 + r16;
                af[mf] = *(const short8*)(lds + row * 128 + (((ksl * 4 + g) ^ (row & 7)) << 4));
            }
            #pragma unroll
            for (int nf = 0; nf < 4; nf++) {
                const int row = wc * 64 + nf * 16 + r16;
                bfv[nf] = *(const short8*)(lds + 16384 + row * 128 +
                                           (((ksl * 4 + g) ^ (row & 7)) << 4));
            }
            __builtin_amdgcn_s_setprio(1);
            #pragma unroll
            for (int mf = 0; mf < 4; mf++)
                #pragma unroll
                for (int nf = 0; nf < 4; nf++)
                    acc[mf][nf] = __builtin_amdgcn_mfma_f32_16x16x32_bf16(af[mf], bfv[nf], acc[mf][nf], 0, 0, 0);
            __builtin_amdgcn_s_setprio(0);
        }
        asm volatile("s_waitcnt lgkmcnt(0)" ::: "memory");
        __builtin_amdgcn_s_barrier();     // reads done; next stage (or repack) may overwrite
    }

    // ---- EPI roles + W prefetch (VMEM only; overlaps repack)
    const int zg = wid >> 1, ik = wid & 1;
    const short* wt = (const short*)WoutT;
    short8 Wr[4][2];
    #pragma unroll
    for (int d = 0; d < 4; d++)
        #pragma unroll
        for (int nf = 0; nf < 2; nf++)
            Wr[d][nf] = *(const short8*)&wt[(zg * 32 + nf * 16 + r16) * 1024 +
                                            ik * 512 + d * 32 + g * 8];
    float bv0 = 0.f, bv1 = 0.f;
    if (ik == 0) { bv0 = bout[zg * 32 + r16]; bv1 = bout[zg * 32 + 16 + r16]; }

    // ---- repack acc -> sP[32 p][1024 ck] bf16 (64KB), b64 writes
    #pragma unroll
    for (int nf = 0; nf < 4; nf++) {
        #pragma unroll
        for (int mf = 0; mf < 4; mf++) {
            const int p  = (wc * 2 + (nf >> 1)) * 4 + wr * 2 + (mf >> 1);
            const int ck = ((nf & 1) * 16 + r16) * 32 + (mf & 1) * 16 + g * 4;
            const int gr = ck >> 3;
            short4v v;
            v.x = f2bf(acc[mf][nf][0]); v.y = f2bf(acc[mf][nf][1]);
            v.z = f2bf(acc[mf][nf][2]); v.w = f2bf(acc[mf][nf][3]);
            *(short4v*)(lds + p * 2048 + ((gr ^ (p & 7)) << 4) + ((ck & 7) << 1)) = v;
        }
    }
    asm volatile("s_waitcnt lgkmcnt(0)" ::: "memory");
    __builtin_amdgcn_s_barrier();     // sP complete

    // ---- EPI: 16 ks of {2 sP reads (rows r16, 16+r16), 4 MFMA, roll W}
    f32x4 e[2][2];
    e[0][0] = (f32x4){bv0, bv0, bv0, bv0};
    e[0][1] = (f32x4){bv1, bv1, bv1, bv1};
    e[1][0] = (f32x4){bv0, bv0, bv0, bv0};
    e[1][1] = (f32x4){bv1, bv1, bv1, bv1};
    if (ik) { e[0][0] = e[0][1] = e[1][0] = e[1][1] = (f32x4){0.f, 0.f, 0.f, 0.f}; }

    #pragma unroll
    for (int ks = 0; ks < 16; ks++) {
        const int gr = ik * 64 + ks * 4 + g;
        short8 pv0 = *(const short8*)(lds + r16 * 2048 + ((gr ^ (r16 & 7)) << 4));
        short8 pv1 = *(const short8*)(lds + (16 + r16) * 2048 + ((gr ^ (r16 & 7)) << 4));
        __builtin_amdgcn_s_setprio(1);
        e[0][0] = __builtin_amdgcn_mfma_f32_16x16x32_bf16(pv0, Wr[ks & 3][0], e[0][0], 0, 0, 0);
        e[0][1] = __builtin_amdgcn_mfma_f32_16x16x32_bf16(pv0, Wr[ks & 3][1], e[0][1], 0, 0, 0);
        e[1][0] = __builtin_amdgcn_mfma_f32_16x16x32_bf16(pv1, Wr[ks & 3][0], e[1][0], 0, 0, 0);
        e[1][1] = __builtin_amdgcn_mfma_f32_16x16x32_bf16(pv1, Wr[ks & 3][1], e[1][1], 0, 0, 0);
        __builtin_amdgcn_s_setprio(0);
        if (ks < 12) {
            #pragma unroll
            for (int nf = 0; nf < 2; nf++)
                Wr[ks & 3][nf] = *(const short8*)&wt[(zg * 32 + nf * 16 + r16) * 1024 +
                                                     ik * 512 + (ks + 4) * 32 + g * 8];
        }
    }
    asm volatile("s_waitcnt lgkmcnt(0)" ::: "memory");
    __builtin_amdgcn_s_barrier();     // all sP reads done; rbuf may overwrite

    // ---- cross-wave ik reduction: rbuf [(zg*4+q)*64 + lane] * 16B (16KB at lds[0..16K))
    if (ik) {
        #pragma unroll
        for (int pf = 0; pf < 2; pf++)
            #pragma unroll
            for (int nf = 0; nf < 2; nf++)
                *(f32x4*)(lds + ((zg * 4 + pf * 2 + nf) * 64 + lane) * 16) = e[pf][nf];
    }
    asm volatile("s_waitcnt lgkmcnt(0)" ::: "memory");
    __builtin_amdgcn_s_barrier();

    if (!ik) {
        #pragma unroll
        for (int pf = 0; pf < 2; pf++) {
            #pragma unroll
            for (int nf = 0; nf < 2; nf++) {
                f32x4 o = *(const f32x4*)(lds + ((zg * 4 + pf * 2 + nf) * 64 + lane) * 16);
                const int z = zg * 32 + nf * 16 + r16;
                #pragma unroll
                for (int reg = 0; reg < 4; reg++) {
                    const int p  = pf * 16 + g * 4 + reg;
                    const int ig = bi * 8 + (p >> 2), jg = bj * 4 + (p & 3);
                    out[((size_t)(ig * 256 + jg)) * 128 + z] =
                        (e[pf][nf][reg] + o[reg]) * (1.f / 128.f);
                }
            }
        }
    }
}

extern "C" void kernel_launch(void* const* d_in, const int* in_sizes, int n_in,
                              void* d_out, int out_size, void* d_ws, size_t ws_size,
                              hipStream_t stream) {
    const float* mm    = (const float*)d_in[0];
    const float* gamma = (const float*)d_in[1];
    const float* beta  = (const float*)d_in[2];
    const float* W1    = (const float*)d_in[3];
    const float* b1    = (const float*)d_in[4];
    const float* W2    = (const float*)d_in[5];
    const float* b2    = (const float*)d_in[6];
    const float* Wout  = (const float*)d_in[7];
    const float* bout  = (const float*)d_in[8];

    __hip_bfloat16* Ap    = (__hip_bfloat16*)((char*)d_ws + WS_A);
    __hip_bfloat16* Bp    = (__hip_bfloat16*)((char*)d_ws + WS_B);
    __hip_bfloat16* WoutT = (__hip_bfloat16*)((char*)d_ws + WS_WT);
    __hip_bfloat16* W12bf = (__hip_bfloat16*)((char*)d_ws + WS_W12);
    float* out = (float*)d_out;

    (void)hipFuncSetAttribute(reinterpret_cast<const void*>(k_gemm8),
                              hipFuncAttributeMaxDynamicSharedMemorySize, 65536);

    hipLaunchKernelGGL(k_prep, dim3(576), dim3(256), 0, stream, Wout, W1, W2, WoutT, W12bf);
    hipLaunchKernelGGL(k_lnproj, dim3(512), dim3(256), 0, stream,
                       mm, gamma, beta, b1, b2, W12bf, Ap, Bp);
    hipLaunchKernelGGL(k_gemm8, dim3(2048), dim3(512), 65536, stream,
                       Ap, Bp, WoutT, bout, out);
}

// Round 9
// 94.808 us; speedup vs baseline: 1.0903x; 1.0903x over previous
//
#include <hip/hip_runtime.h>
#include <hip/hip_bf16.h>

typedef __attribute__((ext_vector_type(8))) short short8;
typedef __attribute__((ext_vector_type(4))) short short4v;
typedef __attribute__((ext_vector_type(4))) float f32x4;

// ws: A' [8192][128] bf16 (2MB) | B' [8192][128] bf16 (2MB) |
//     WoutT [128][1024] bf16 (256KB) | W12bf [64][256] bf16 (32KB)
#define WS_A   0
#define WS_B   (8192 * 128 * 2)
#define WS_WT  (2 * 8192 * 128 * 2)
#define WS_W12 (WS_WT + 128 * 1024 * 2)

static __device__ __forceinline__ short f2bf(float x) {
    __hip_bfloat16 h = __float2bfloat16(x);
    return *reinterpret_cast<short*>(&h);
}

typedef __attribute__((address_space(3))) unsigned int lds_u32;
typedef const __attribute__((address_space(1))) unsigned int glb_u32;
static __device__ __forceinline__ void stage16(const void* g, void* l) {
    __builtin_amdgcn_global_load_lds((glb_u32*)g, (lds_u32*)l, 16, 0, 0);
}

// ---------------- Kernel 0: Wout -> bf16 [z][ck]; W1|W2 -> bf16 [64 c][256 d] ----------------
__global__ __launch_bounds__(256) void k_prep(const float* __restrict__ Wout,
                                              const float* __restrict__ W1,
                                              const float* __restrict__ W2,
                                              __hip_bfloat16* __restrict__ WoutT,
                                              __hip_bfloat16* __restrict__ W12bf) {
    int idx = blockIdx.x * 256 + threadIdx.x;
    if (blockIdx.x < 512) {
        int z = idx >> 10, ck = idx & 1023;
        WoutT[idx] = __float2bfloat16(Wout[ck * 128 + z]);
    } else {
        idx -= 512 * 256;                  // 0..16383
        int c = idx >> 8, d = idx & 255;
        W12bf[idx] = __float2bfloat16(c < 32 ? W1[d * 32 + c] : W2[d * 32 + (c - 32)]);
    }
}

// ---------------- Kernel 1: LayerNorm + dual projection via MFMA (unchanged) ----------------
__global__ __launch_bounds__(256) void k_lnproj(const float* __restrict__ mm,
                                                const float* __restrict__ gamma,
                                                const float* __restrict__ beta,
                                                const float* __restrict__ b1,
                                                const float* __restrict__ b2,
                                                const __hip_bfloat16* __restrict__ W12bf,
                                                __hip_bfloat16* __restrict__ Ap,
                                                __hip_bfloat16* __restrict__ Bp) {
    __shared__ char sMN[4][8192];      // per-wave [16 rows][256 d] bf16, XOR-swizzled
    __shared__ char sW[32768];         // [64 c][256 d] bf16, XOR-swizzled (512B rows)
    const int t    = threadIdx.x;
    const int lane = t & 63;
    const int wid  = t >> 6;
    const int gw   = blockIdx.x * 4 + wid;   // 0..2047
    const int i_   = gw & 255;
    const int sb   = (gw >> 8) * 16;

    #pragma unroll
    for (int it = 0; it < 8; it++) {
        const int idx = it * 256 + t;
        const int row = idx >> 5;
        const int L   = (idx & 31) * 16;
        *(short8*)(sW + row * 512 + (L ^ ((row & 7) << 4))) =
            *(const short8*)((const short*)W12bf + idx * 8);
    }

    float4 g4  = *(const float4*)&gamma[lane * 4];
    float4 be4 = *(const float4*)&beta[lane * 4];
    char* my = sMN[wid];

    #pragma unroll
    for (int rr = 0; rr < 16; rr++) {
        float4 x = *(const float4*)&mm[((size_t)(sb + rr) * 256 + i_) * 256 + lane * 4];
        float s  = x.x + x.y + x.z + x.w;
        float ss = x.x * x.x + x.y * x.y + x.z * x.z + x.w * x.w;
        #pragma unroll
        for (int off = 32; off; off >>= 1) {
            s  += __shfl_xor(s, off);
            ss += __shfl_xor(ss, off);
        }
        float mu  = s * (1.f / 256.f);
        float var = ss * (1.f / 256.f) - mu * mu;
        float rs  = rsqrtf(var + 1e-5f);
        short4v v;
        v.x = f2bf((x.x - mu) * rs * g4.x + be4.x);
        v.y = f2bf((x.y - mu) * rs * g4.y + be4.y);
        v.z = f2bf((x.z - mu) * rs * g4.z + be4.z);
        v.w = f2bf((x.w - mu) * rs * g4.w + be4.w);
        *(short4v*)(my + rr * 512 + ((lane * 8) ^ ((rr & 7) << 4))) = v;
    }
    __syncthreads();

    const int g = lane >> 4, r16 = lane & 15;

    f32x4 acc[4];
    #pragma unroll
    for (int nf = 0; nf < 4; nf++) {
        int col = nf * 16 + r16;
        float bv = (col < 32) ? b1[col] : b2[col - 32];
        acc[nf] = (f32x4){bv, bv, bv, bv};
    }
    #pragma unroll
    for (int ks = 0; ks < 8; ks++) {
        const int L = ks * 64 + g * 16;
        short8 af = *(const short8*)(my + r16 * 512 + (L ^ ((r16 & 7) << 4)));
        #pragma unroll
        for (int nf = 0; nf < 4; nf++) {
            short8 bfv = *(const short8*)(sW + (nf * 16 + r16) * 512 + (L ^ ((r16 & 7) << 4)));
            acc[nf] = __builtin_amdgcn_mfma_f32_16x16x32_bf16(af, bfv, acc[nf], 0, 0, 0);
        }
    }
    #pragma unroll
    for (int nf = 0; nf < 4; nf++) {
        int col = nf * 16 + r16;
        short* Out = (short*)((col < 32) ? Ap : Bp);
        int cr = col & 31;
        short4v v;
        v.x = f2bf(acc[nf][0]); v.y = f2bf(acc[nf][1]);
        v.z = f2bf(acc[nf][2]); v.w = f2bf(acc[nf][3]);
        *(short4v*)&Out[(i_ * 32 + cr) * 128 + sb + g * 4] = v;
    }
}

// ---------------- Kernel 2: 128jk x 256ic tile, 64KB LDS, 2 blocks/CU ----------------
// LDS 64KB: [0,16K) B0 | [16K,48K) A0 (later A1) | [48K,64K) B1. A1 reg-staged (T14).
// After main: sP [32 p][2048B] rows, swizzle byte = p*2048 + (L ^ ((((L>>7)^p)&7)<<4)).
// EPI: 8 waves x 16 z each (z = wid*16+r16); M=32 (2 pf), K=1024; rolling Wr[4]; no reduction.
extern __shared__ char lds[];

__global__ __launch_bounds__(512, 4) void k_gemm9(const __hip_bfloat16* __restrict__ Apb,
                                                  const __hip_bfloat16* __restrict__ Bpb,
                                                  const __hip_bfloat16* __restrict__ WoutT,
                                                  const float* __restrict__ bout,
                                                  float* __restrict__ out) {
    const int t = threadIdx.x, lane = t & 63, wid = t >> 6;
    const int g = lane >> 4, r16 = lane & 15;
    const int wr = wid >> 2, wc = wid & 3;            // wr: jk half (64), wc: ic quarter (64)
    const int bid = (blockIdx.x & 7) * 256 + (blockIdx.x >> 3);   // XCD swizzle (2048%8==0)
    const int bi = bid >> 6, bj = bid & 63;           // bi: 32 ic-blocks, bj: 64 jk-blocks

    const short* gA = (const short*)Apb + (size_t)bi * 256 * 128;   // 256 ic rows
    const short* gB = (const short*)Bpb + (size_t)bj * 128 * 128;   // 128 jk rows

    const int srow8 = lane >> 3;
    const int sgran = (lane & 7) ^ srow8;             // pre-swizzled source granule

    // ---- issue ALL staging upfront: B0(2), A0(4) gload_lds; B1(2) gload_lds; A1(4) -> regs
    #pragma unroll
    for (int it = 0; it < 2; it++) {
        const int row = it * 64 + wid * 8 + srow8;
        stage16(gB + row * 128 + sgran * 8, lds + it * 8192 + wid * 1024);
    }
    #pragma unroll
    for (int it = 0; it < 4; it++) {
        const int row = it * 64 + wid * 8 + srow8;
        stage16(gA + row * 128 + sgran * 8, lds + 16384 + it * 8192 + wid * 1024);
    }
    #pragma unroll
    for (int it = 0; it < 2; it++) {
        const int row = it * 64 + wid * 8 + srow8;
        stage16(gB + row * 128 + 64 + sgran * 8, lds + 49152 + it * 8192 + wid * 1024);
    }
    short8 a1r[4];
    #pragma unroll
    for (int it = 0; it < 4; it++) {
        const int row = it * 64 + wid * 8 + srow8;
        a1r[it] = *(const short8*)(gA + row * 128 + 64 + sgran * 8);
    }

    asm volatile("s_waitcnt vmcnt(6)" ::: "memory");   // B0+A0 landed
    __builtin_amdgcn_s_barrier();

    f32x4 acc[4][4];
    #pragma unroll
    for (int mf = 0; mf < 4; mf++)
        #pragma unroll
        for (int nf = 0; nf < 4; nf++)
            acc[mf][nf] = (f32x4){0.f, 0.f, 0.f, 0.f};

    #pragma unroll
    for (int kh = 0; kh < 2; kh++) {
        const char* sBb = lds + (kh ? 49152 : 0);
        const char* sAb = lds + 16384;
        #pragma unroll
        for (int ksl = 0; ksl < 2; ksl++) {
            short8 af[4], bfv[4];
            #pragma unroll
            for (int mf = 0; mf < 4; mf++) {
                const int row = wr * 64 + mf * 16 + r16;
                af[mf] = *(const short8*)(sBb + row * 128 + (((ksl * 4 + g) ^ (row & 7)) << 4));
            }
            #pragma unroll
            for (int nf = 0; nf < 4; nf++) {
                const int row = wc * 64 + nf * 16 + r16;
                bfv[nf] = *(const short8*)(sAb + row * 128 + (((ksl * 4 + g) ^ (row & 7)) << 4));
            }
            __builtin_amdgcn_s_setprio(1);
            #pragma unroll
            for (int mf = 0; mf < 4; mf++)
                #pragma unroll
                for (int nf = 0; nf < 4; nf++)
                    acc[mf][nf] = __builtin_amdgcn_mfma_f32_16x16x32_bf16(af[mf], bfv[nf], acc[mf][nf], 0, 0, 0);
            __builtin_amdgcn_s_setprio(0);
        }
        if (kh == 0) {
            // A0 reads done -> overwrite A region with reg-staged A1; B1 already landing
            asm volatile("s_waitcnt lgkmcnt(0)" ::: "memory");
            __builtin_amdgcn_s_barrier();
            asm volatile("s_waitcnt vmcnt(0)" ::: "memory");   // B1 staged, a1r valid
            #pragma unroll
            for (int it = 0; it < 4; it++)
                *(short8*)(lds + 16384 + it * 8192 + wid * 1024 + (lane & 63) * 16) = a1r[it];
            asm volatile("s_waitcnt lgkmcnt(0)" ::: "memory");
            __builtin_amdgcn_s_barrier();
        }
    }
    asm volatile("s_waitcnt lgkmcnt(0)" ::: "memory");
    __builtin_amdgcn_s_barrier();     // all A/B reads done; sP may overwrite

    // ---- EPI role + W prefetch (VMEM overlaps repack)
    const int z = wid * 16 + r16;
    const short* wtz = (const short*)WoutT + z * 1024 + g * 8;
    short8 Wr[4];
    #pragma unroll
    for (int d = 0; d < 4; d++) Wr[d] = *(const short8*)&wtz[d * 32];
    const float bv = bout[z];

    // ---- repack acc -> sP[32 p][2048B], b64 writes, gemm6-style key (4-way floor)
    #pragma unroll
    for (int nf = 0; nf < 4; nf++) {
        #pragma unroll
        for (int mf = 0; mf < 4; mf++) {
            const int p = (wc * 2 + (nf >> 1)) * 4 + wr * 2 + (mf >> 1);
            const int L = r16 * 64 + (nf & 1) * 1024 + (mf & 1) * 32 + g * 8;
            short4v v;
            v.x = f2bf(acc[mf][nf][0]); v.y = f2bf(acc[mf][nf][1]);
            v.z = f2bf(acc[mf][nf][2]); v.w = f2bf(acc[mf][nf][3]);
            *(short4v*)(lds + p * 2048 + (L ^ ((((L >> 7) ^ p) & 7) << 4))) = v;
        }
    }
    asm volatile("s_waitcnt lgkmcnt(0)" ::: "memory");
    __builtin_amdgcn_s_barrier();     // sP complete

    // ---- EPI: 32 ks of {2 sP reads (16-row frags), 2 MFMA, roll W}
    f32x4 e0 = (f32x4){bv, bv, bv, bv};
    f32x4 e1 = (f32x4){bv, bv, bv, bv};

    #pragma unroll
    for (int ks = 0; ks < 32; ks++) {
        const int L = ks * 64 + g * 16;
        const int row0 = r16, row1 = 16 + r16;
        short8 pv0 = *(const short8*)(lds + row0 * 2048 + (L ^ ((((L >> 7) ^ row0) & 7) << 4)));
        short8 pv1 = *(const short8*)(lds + row1 * 2048 + (L ^ ((((L >> 7) ^ row1) & 7) << 4)));
        __builtin_amdgcn_s_setprio(1);
        e0 = __builtin_amdgcn_mfma_f32_16x16x32_bf16(pv0, Wr[ks & 3], e0, 0, 0, 0);
        e1 = __builtin_amdgcn_mfma_f32_16x16x32_bf16(pv1, Wr[ks & 3], e1, 0, 0, 0);
        __builtin_amdgcn_s_setprio(0);
        if (ks < 28) Wr[ks & 3] = *(const short8*)&wtz[(ks + 4) * 32];
    }

    // ---- store: p = pf*16 + g*4 + reg; ig = bi*8 + p>>2, jg = bj*4 + p&3
    #pragma unroll
    for (int reg = 0; reg < 4; reg++) {
        const int p0 = g * 4 + reg;
        const int p1 = 16 + g * 4 + reg;
        out[((size_t)((bi * 8 + (p0 >> 2)) * 256 + bj * 4 + (p0 & 3))) * 128 + z] =
            e0[reg] * (1.f / 128.f);
        out[((size_t)((bi * 8 + (p1 >> 2)) * 256 + bj * 4 + (p1 & 3))) * 128 + z] =
            e1[reg] * (1.f / 128.f);
    }
}

extern "C" void kernel_launch(void* const* d_in, const int* in_sizes, int n_in,
                              void* d_out, int out_size, void* d_ws, size_t ws_size,
                              hipStream_t stream) {
    const float* mm    = (const float*)d_in[0];
    const float* gamma = (const float*)d_in[1];
    const float* beta  = (const float*)d_in[2];
    const float* W1    = (const float*)d_in[3];
    const float* b1    = (const float*)d_in[4];
    const float* W2    = (const float*)d_in[5];
    const float* b2    = (const float*)d_in[6];
    const float* Wout  = (const float*)d_in[7];
    const float* bout  = (const float*)d_in[8];

    __hip_bfloat16* Ap    = (__hip_bfloat16*)((char*)d_ws + WS_A);
    __hip_bfloat16* Bp    = (__hip_bfloat16*)((char*)d_ws + WS_B);
    __hip_bfloat16* WoutT = (__hip_bfloat16*)((char*)d_ws + WS_WT);
    __hip_bfloat16* W12bf = (__hip_bfloat16*)((char*)d_ws + WS_W12);
    float* out = (float*)d_out;

    (void)hipFuncSetAttribute(reinterpret_cast<const void*>(k_gemm9),
                              hipFuncAttributeMaxDynamicSharedMemorySize, 65536);

    hipLaunchKernelGGL(k_prep, dim3(576), dim3(256), 0, stream, Wout, W1, W2, WoutT, W12bf);
    hipLaunchKernelGGL(k_lnproj, dim3(512), dim3(256), 0, stream,
                       mm, gamma, beta, b1, b2, W12bf, Ap, Bp);
    hipLaunchKernelGGL(k_gemm9, dim3(2048), dim3(512), 65536, stream,
                       Ap, Bp, WoutT, bout, out);
}